// Round 4
// baseline (287.233 us; speedup 1.0000x reference)
//
#include <hip/hip_runtime.h>

typedef unsigned short u16;
typedef unsigned int u32;
typedef __attribute__((ext_vector_type(8))) short bf16x8;
typedef __attribute__((ext_vector_type(4))) float f32x4;

#define NPTS 2048
#define CFEAT 256
#define NS 32
#define MTOT 262144           // 4*2048*32
#define NBLK 4096             // MTOT/64 m-tiles
#define INV_N (1.0f/262144.0f)

__device__ __forceinline__ float bf2f(u16 u) {
    union { u32 i; float f; } v; v.i = ((u32)u) << 16; return v.f;
}
__device__ __forceinline__ u16 f2bf(float f) {
    union { float f; u32 i; } v; v.f = f;
    u32 i = v.i;
    return (u16)((i + 0x7fffu + ((i >> 16) & 1u)) >> 16);
}

// async 1 KB wave copy: lds base wave-uniform, global per-lane (+lane*16B)
__device__ __forceinline__ void stage1k(u16* lds, const u16* g, int lane) {
#if defined(__has_builtin) && __has_builtin(__builtin_amdgcn_global_load_lds)
    __builtin_amdgcn_global_load_lds((const __attribute__((address_space(1))) void*)(g + lane * 8),
                                     (__attribute__((address_space(3))) void*)lds, 16, 0, 0);
#else
    *(uint4*)(lds + lane * 8) = *(const uint4*)(g + lane * 8);
#endif
}

// ---------------- prep: K-tiled weight packs. Wp1T[ks(9)][n(256)][kc(32)], Wp2T[ks(8)][n][kc] ----------------
__global__ __launch_bounds__(256) void prep_k(const float* __restrict__ W1, const float* __restrict__ W2,
                                              u16* __restrict__ Wp1T, u16* __restrict__ Wp2T) {
    int o = blockIdx.x, t = threadIdx.x;
    int ks = t >> 5, kc = t & 31;
    Wp1T[(ks * 256 + o) * 32 + kc] = f2bf(W1[o * 259 + 3 + t]);
    Wp2T[(ks * 256 + o) * 32 + kc] = f2bf(W2[o * 256 + t]);
    if (t < 32) Wp1T[(8 * 256 + o) * 32 + t] = (t < 3) ? f2bf(W1[o * 259 + t]) : (u16)0;
}

// ---------------- cylinder query: wave per point, ballot compaction ----------------
__global__ __launch_bounds__(256) void query_k(const float* __restrict__ xyz, const float* __restrict__ rot,
                                               int* __restrict__ idx) {
    int pid = blockIdx.x * 4 + (threadIdx.x >> 6);
    int lane = threadIdx.x & 63;
    int b = pid >> 11, p = pid & 2047;
    const float* xb = xyz + (size_t)b * NPTS * 3;
    float px = xb[p * 3 + 0], py = xb[p * 3 + 1], pz = xb[p * 3 + 2];
    const float* rp = rot + (size_t)pid * 9;
    float r00 = rp[0], r01 = rp[1], r02 = rp[2];
    float r10 = rp[3], r11 = rp[4], r12 = rp[5];
    float r20 = rp[6], r21 = rp[7], r22 = rp[8];
    int cnt = 0, first = 0;
    for (int n0 = 0; n0 < NPTS && cnt < NS; n0 += 64) {
        int n = n0 + lane;
        float dx = __fsub_rn(xb[n * 3 + 0], px);
        float dy = __fsub_rn(xb[n * 3 + 1], py);
        float dz = __fsub_rn(xb[n * 3 + 2], pz);
        float a0 = __fadd_rn(__fadd_rn(__fmul_rn(r00, dx), __fmul_rn(r01, dy)), __fmul_rn(r02, dz));
        float a1 = __fadd_rn(__fadd_rn(__fmul_rn(r10, dx), __fmul_rn(r11, dy)), __fmul_rn(r12, dz));
        float a2 = __fadd_rn(__fadd_rn(__fmul_rn(r20, dx), __fmul_rn(r21, dy)), __fmul_rn(r22, dz));
        float t2 = __fadd_rn(__fmul_rn(a1, a1), __fmul_rn(a2, a2));
        bool valid = (t2 < 0.0025f) && (a0 > -0.02f) && (a0 < 0.04f);
        unsigned long long bal = __ballot(valid);
        if (cnt == 0 && bal) first = n0 + __builtin_ctzll(bal);
        int rank = __builtin_popcountll(bal & ((1ull << lane) - 1ull));
        int slot = cnt + rank;
        if (valid && slot < NS) idx[(size_t)pid * NS + slot] = n;
        cnt += __builtin_popcountll(bal);
    }
    int filled = cnt < NS ? cnt : NS;
    if (lane >= filled && lane < NS) idx[(size_t)pid * NS + lane] = (cnt > 0) ? first : 0;
}

// ---------------- features (B,C,N) fp32 -> featT (B,N,C) bf16 ----------------
__global__ __launch_bounds__(256) void featT_k(const float* __restrict__ feat, u16* __restrict__ featT) {
    __shared__ float sm[32 * 33];
    int b = blockIdx.z;
    int n0 = blockIdx.x * 32, c0 = blockIdx.y * 32;
    int t = threadIdx.x, x = t & 31, y = t >> 5;
    #pragma unroll
    for (int rr = 0; rr < 4; rr++) {
        int c = c0 + y + rr * 8;
        sm[(y + rr * 8) * 33 + x] = feat[((size_t)(b * CFEAT + c)) * NPTS + n0 + x];
    }
    __syncthreads();
    #pragma unroll
    for (int rr = 0; rr < 4; rr++) {
        int n = n0 + y + rr * 8;
        featT[((size_t)(b * NPTS + n)) * CFEAT + c0 + x] = f2bf(sm[x * 33 + (y + rr * 8)]);
    }
}

// ---------------- gxyz: rotated, scaled neighbor offsets, (MTOT,4) bf16 ----------------
__global__ __launch_bounds__(256) void gxyz_k(const float* __restrict__ xyz, const float* __restrict__ rot,
                                              const int* __restrict__ idx, u16* __restrict__ gxyz) {
    int m = blockIdx.x * 256 + threadIdx.x;
    int pid = m >> 5;
    int b = pid >> 11, p = pid & 2047;
    int i = idx[m];
    const float* xb = xyz + (size_t)b * NPTS * 3;
    float dx = (xb[i * 3 + 0] - xb[p * 3 + 0]) * 20.0f;
    float dy = (xb[i * 3 + 1] - xb[p * 3 + 1]) * 20.0f;
    float dz = (xb[i * 3 + 2] - xb[p * 3 + 2]) * 20.0f;
    const float* rp = rot + (size_t)pid * 9;
    float g0 = dx * rp[0] + dy * rp[3] + dz * rp[6];
    float g1 = dx * rp[1] + dy * rp[4] + dz * rp[7];
    float g2 = dx * rp[2] + dy * rp[5] + dz * rp[8];
    uint2 v;
    v.x = (u32)f2bf(g0) | ((u32)f2bf(g1) << 16);
    v.y = (u32)f2bf(g2);
    *(uint2*)(gxyz + (size_t)m * 4) = v;
}

// ---------------- pass 1: GEMM1 (A direct from global, B async dbuf), stats1 + y1 frag spill ----------------
__global__ __launch_bounds__(256, 3) void gemm1_k(
    const u16* __restrict__ featT, const u16* __restrict__ gxyz, const int* __restrict__ idx,
    const u16* __restrict__ Wp1T, float* __restrict__ psum, float* __restrict__ psq,
    uint2* __restrict__ y1f)
{
    __shared__ __attribute__((aligned(16))) u16 Bs[2][8192];   // 2 x 16 KB

    const int tid = threadIdx.x;
    const int lane = tid & 63, wave = tid >> 6;
    const int quad = lane >> 4, tl = lane & 15;
    const int bx = blockIdx.x;
    const int m0 = bx * 64;
    const int bofs = (bx >> 10) * NPTS * CFEAT;   // batch row offset

    // per-lane A row bases (rows i*16+tl)
    int rb[4];
    #pragma unroll
    for (int i = 0; i < 4; i++) rb[i] = bofs + idx[m0 + i * 16 + tl] * CFEAT;

    // prefetch A fragments for ks=0
    bf16x8 af[4];
    #pragma unroll
    for (int i = 0; i < 4; i++) af[i] = *(const bf16x8*)(featT + rb[i] + quad * 8);

    // issue B tile ks=0 into buf 0 (4 x 1KB per wave)
    #pragma unroll
    for (int c = 0; c < 4; c++)
        stage1k(&Bs[0][wave * 2048 + c * 512], Wp1T + wave * 2048 + c * 512, lane);

    f32x4 acc[4][4];
    #pragma unroll
    for (int i = 0; i < 4; i++)
        #pragma unroll
        for (int j = 0; j < 4; j++) acc[i][j] = (f32x4){0.f, 0.f, 0.f, 0.f};

    for (int ks = 0; ks < 9; ks++) {
        __syncthreads();   // drains async B(ks) + af(ks); all waves done reading buf[(ks+1)&1]
        if (ks < 8) {      // issue B(ks+1) into other buffer; flies under this step's MFMAs
            const u16* gsrc = Wp1T + (ks + 1) * 8192;
            #pragma unroll
            for (int c = 0; c < 4; c++)
                stage1k(&Bs[(ks + 1) & 1][wave * 2048 + c * 512], gsrc + wave * 2048 + c * 512, lane);
        }
        bf16x8 bv[4];
        #pragma unroll
        for (int j = 0; j < 4; j++)
            bv[j] = *(const bf16x8*)(&Bs[ks & 1][(wave * 64 + j * 16 + tl) * 32 + quad * 8]);

        bf16x8 afn[4];
        if (ks < 7) {
            #pragma unroll
            for (int i = 0; i < 4; i++)
                afn[i] = *(const bf16x8*)(featT + rb[i] + (ks + 1) * 32 + quad * 8);
        } else if (ks == 7) {   // next tile is the xyz tile: [g0,g1,g2,0...] on quad 0, zeros elsewhere
            #pragma unroll
            for (int i = 0; i < 4; i++) {
                union { bf16x8 v; uint4 u; } cv;
                cv.u = make_uint4(0, 0, 0, 0);
                if (quad == 0) {
                    uint2 g2 = *(const uint2*)(gxyz + (size_t)(m0 + i * 16 + tl) * 4);
                    cv.u.x = g2.x; cv.u.y = g2.y;
                }
                afn[i] = cv.v;
            }
        }
        #pragma unroll
        for (int i = 0; i < 4; i++)
            #pragma unroll
            for (int j = 0; j < 4; j++)
                acc[i][j] = __builtin_amdgcn_mfma_f32_16x16x32_bf16(af[i], bv[j], acc[i][j], 0, 0, 0);
        #pragma unroll
        for (int i = 0; i < 4; i++) af[i] = afn[i];
    }

    // epilogue: spill y1 frags (bf16), stats on the rounded values, coalesced psum/psq
    #pragma unroll
    for (int j = 0; j < 4; j++) {
        float s = 0.f, q2 = 0.f;
        #pragma unroll
        for (int i = 0; i < 4; i++) {
            float v0 = acc[i][j][0], v1 = acc[i][j][1], v2 = acc[i][j][2], v3 = acc[i][j][3];
            u32 lo = (u32)f2bf(v0) | ((u32)f2bf(v1) << 16);
            u32 hi = (u32)f2bf(v2) | ((u32)f2bf(v3) << 16);
            y1f[((size_t)(bx * 4 + wave) * 16 + i * 4 + j) * 64 + lane] = make_uint2(lo, hi);
            v0 = bf2f((u16)(lo & 0xffff)); v1 = bf2f((u16)(lo >> 16));
            v2 = bf2f((u16)(hi & 0xffff)); v3 = bf2f((u16)(hi >> 16));
            s += v0 + v1 + v2 + v3;
            q2 += v0 * v0 + v1 * v1 + v2 * v2 + v3 * v3;
        }
        s += __shfl_xor(s, 16); s += __shfl_xor(s, 32);
        q2 += __shfl_xor(q2, 16); q2 += __shfl_xor(q2, 32);
        if (quad == 0) {
            int col = wave * 64 + j * 16 + tl;
            psum[(size_t)bx * 256 + col] = s;
            psq[(size_t)bx * 256 + col] = q2;
        }
    }
}

// ---------------- pass 2: reload y1 frags, norm+relu -> LDS, GEMM2 (B async), stats2 + max/min ----------------
__global__ __launch_bounds__(256, 3) void gemm2_k(
    const uint2* __restrict__ y1f, const u16* __restrict__ Wp2T, const float* __restrict__ ab1,
    float* __restrict__ psum, float* __restrict__ psq,
    float* __restrict__ ymax, float* __restrict__ ymin)
{
    __shared__ __attribute__((aligned(16))) u16 Bs[8192];       // 16 KB
    __shared__ __attribute__((aligned(16))) u16 y1s[64 * 264];  // 33.8 KB
    const int tid = threadIdx.x;
    const int lane = tid & 63, wave = tid >> 6;
    const int quad = lane >> 4, tl = lane & 15;
    const int bx = blockIdx.x;

    // reload own pass-1 fragments (coalesced), normalize+relu, deposit to LDS (C-layout -> A-layout)
    #pragma unroll
    for (int j = 0; j < 4; j++) {
        int col = wave * 64 + j * 16 + tl;
        float a = ab1[col], bb = ab1[256 + col];
        #pragma unroll
        for (int i = 0; i < 4; i++) {
            uint2 v = y1f[((size_t)(bx * 4 + wave) * 16 + i * 4 + j) * 64 + lane];
            float f0 = bf2f((u16)(v.x & 0xffff)), f1 = bf2f((u16)(v.x >> 16));
            float f2 = bf2f((u16)(v.y & 0xffff)), f3 = bf2f((u16)(v.y >> 16));
            int rbi = (i * 16 + quad * 4) * 264 + col;
            y1s[rbi] = f2bf(fmaxf(fmaf(f0, a, bb), 0.f));
            y1s[rbi + 264] = f2bf(fmaxf(fmaf(f1, a, bb), 0.f));
            y1s[rbi + 528] = f2bf(fmaxf(fmaf(f2, a, bb), 0.f));
            y1s[rbi + 792] = f2bf(fmaxf(fmaf(f3, a, bb), 0.f));
        }
    }

    f32x4 acc2[4][4];
    #pragma unroll
    for (int i = 0; i < 4; i++)
        #pragma unroll
        for (int j = 0; j < 4; j++) acc2[i][j] = (f32x4){0.f, 0.f, 0.f, 0.f};

    for (int ks = 0; ks < 8; ks++) {
        const u16* gsrc = Wp2T + ks * 8192;
        #pragma unroll
        for (int c = 0; c < 4; c++)
            stage1k(&Bs[wave * 2048 + c * 512], gsrc + wave * 2048 + c * 512, lane);
        __syncthreads();   // drains B(ks); first iter also covers y1s writes
        bf16x8 afv[4], bv[4];
        #pragma unroll
        for (int i = 0; i < 4; i++) afv[i] = *(const bf16x8*)(y1s + (i * 16 + tl) * 264 + ks * 32 + quad * 8);
        #pragma unroll
        for (int j = 0; j < 4; j++) bv[j] = *(const bf16x8*)(Bs + (wave * 64 + j * 16 + tl) * 32 + quad * 8);
        #pragma unroll
        for (int i = 0; i < 4; i++)
            #pragma unroll
            for (int j = 0; j < 4; j++)
                acc2[i][j] = __builtin_amdgcn_mfma_f32_16x16x32_bf16(afv[i], bv[j], acc2[i][j], 0, 0, 0);
        if (ks < 7) __syncthreads();   // readers done before Bs rewrite
    }

    #pragma unroll
    for (int j = 0; j < 4; j++) {
        int col = wave * 64 + j * 16 + tl;
        float s = 0.f, q2 = 0.f;
        float mx0 = -3.0e38f, mn0 = 3.0e38f, mx1 = -3.0e38f, mn1 = 3.0e38f;
        #pragma unroll
        for (int i = 0; i < 4; i++)
            #pragma unroll
            for (int r = 0; r < 4; r++) {
                float v = acc2[i][j][r];
                s += v; q2 += v * v;
                if (i < 2) { mx0 = fmaxf(mx0, v); mn0 = fminf(mn0, v); }
                else       { mx1 = fmaxf(mx1, v); mn1 = fminf(mn1, v); }
            }
        s += __shfl_xor(s, 16); s += __shfl_xor(s, 32);
        q2 += __shfl_xor(q2, 16); q2 += __shfl_xor(q2, 32);
        mx0 = fmaxf(mx0, __shfl_xor(mx0, 16)); mx0 = fmaxf(mx0, __shfl_xor(mx0, 32));
        mn0 = fminf(mn0, __shfl_xor(mn0, 16)); mn0 = fminf(mn0, __shfl_xor(mn0, 32));
        mx1 = fmaxf(mx1, __shfl_xor(mx1, 16)); mx1 = fmaxf(mx1, __shfl_xor(mx1, 32));
        mn1 = fminf(mn1, __shfl_xor(mn1, 16)); mn1 = fminf(mn1, __shfl_xor(mn1, 32));
        if (quad == 0) {
            psum[(size_t)bx * 256 + col] = s;
            psq[(size_t)bx * 256 + col] = q2;
            size_t p0 = (size_t)(bx * 2) * 256 + col;
            size_t p1 = (size_t)(bx * 2 + 1) * 256 + col;
            ymax[p0] = mx0; ymin[p0] = mn0;
            ymax[p1] = mx1; ymin[p1] = mn1;
        }
    }
}

// ---------------- reduce partials (row-major [bx][256]) -> per-channel (a,b) ----------------
__global__ __launch_bounds__(256) void reduce_k(const float* __restrict__ psum, const float* __restrict__ psq,
                                                const float* __restrict__ gamma, const float* __restrict__ beta,
                                                float* __restrict__ ab) {
    __shared__ float red[8];
    int c = blockIdx.x, t = threadIdx.x;
    float s = 0.f, q = 0.f;
    for (int k = t; k < NBLK; k += 256) { s += psum[(size_t)k * 256 + c]; q += psq[(size_t)k * 256 + c]; }
    #pragma unroll
    for (int o = 32; o >= 1; o >>= 1) { s += __shfl_xor(s, o); q += __shfl_xor(q, o); }
    int lane = t & 63, w = t >> 6;
    if (lane == 0) { red[w] = s; red[4 + w] = q; }
    __syncthreads();
    if (t == 0) {
        float S = red[0] + red[1] + red[2] + red[3];
        float Q = red[4] + red[5] + red[6] + red[7];
        float mu = S * INV_N;
        float var = Q * INV_N - mu * mu;
        float a = gamma[c] * rsqrtf(var + 1e-5f);
        ab[c] = a;
        ab[256 + c] = beta[c] - mu * a;
    }
}

// ---------------- final: relu(a*(a>=0?max:min)+b), transpose -> (B,O,N) ----------------
__global__ __launch_bounds__(256) void final_k(const float* __restrict__ ymax, const float* __restrict__ ymin,
                                               const float* __restrict__ ab, float* __restrict__ out) {
    __shared__ float sm[32 * 33];
    int b = blockIdx.z;
    int n0 = blockIdx.x * 32, o0 = blockIdx.y * 32;
    int t = threadIdx.x, x = t & 31, y = t >> 5;
    #pragma unroll
    for (int rr = 0; rr < 4; rr++) {
        int n = n0 + y + rr * 8;
        int o = o0 + x;
        float a = ab[o], bb = ab[256 + o];
        size_t p = (size_t)(b * NPTS + n) * 256 + o;
        float v = (a >= 0.f) ? ymax[p] : ymin[p];
        sm[(y + rr * 8) * 33 + x] = fmaxf(fmaf(v, a, bb), 0.f);
    }
    __syncthreads();
    #pragma unroll
    for (int rr = 0; rr < 4; rr++)
        out[((size_t)(b * 256 + o0 + y + rr * 8)) * NPTS + n0 + x] = sm[x * 33 + (y + rr * 8)];
}

extern "C" void kernel_launch(void* const* d_in, const int* in_sizes, int n_in,
                              void* d_out, int out_size, void* d_ws, size_t ws_size,
                              hipStream_t stream) {
    const float* xyz    = (const float*)d_in[0];
    const float* feat   = (const float*)d_in[1];
    const float* rot    = (const float*)d_in[2];
    const float* W1     = (const float*)d_in[3];
    const float* gamma1 = (const float*)d_in[4];
    const float* beta1  = (const float*)d_in[5];
    const float* W2     = (const float*)d_in[6];
    const float* gamma2 = (const float*)d_in[7];
    const float* beta2  = (const float*)d_in[8];
    float* out = (float*)d_out;

    char* ws = (char*)d_ws;
    u16*   featT = (u16*)(ws + 0);           //  4,194,304
    int*   idx   = (int*)(ws + 4194304);     //  1,048,576
    u16*   gxyz  = (u16*)(ws + 5242880);     //  2,097,152
    u16*   Wp1T  = (u16*)(ws + 7340032);     //    147,456
    u16*   Wp2T  = (u16*)(ws + 7487488);     //    131,072
    float* ab1   = (float*)(ws + 7618560);   //      2,048
    float* ab2   = (float*)(ws + 7620608);   //      2,048
    float* psum  = (float*)(ws + 7622656);   //  4,194,304
    float* psq   = (float*)(ws + 11816960);  //  4,194,304
    float* ymax  = (float*)(ws + 16011264);  //  8,388,608
    float* ymin  = (float*)(ws + 24399872);  //  8,388,608
    uint2* y1f   = (uint2*)(ws + 32788480);  // 134,217,728

    prep_k<<<256, 256, 0, stream>>>(W1, W2, Wp1T, Wp2T);
    query_k<<<2048, 256, 0, stream>>>(xyz, rot, idx);
    featT_k<<<dim3(64, 8, 4), 256, 0, stream>>>(feat, featT);
    gxyz_k<<<1024, 256, 0, stream>>>(xyz, rot, idx, gxyz);

    gemm1_k<<<NBLK, 256, 0, stream>>>(featT, gxyz, idx, Wp1T, psum, psq, y1f);
    reduce_k<<<256, 256, 0, stream>>>(psum, psq, gamma1, beta1, ab1);
    gemm2_k<<<NBLK, 256, 0, stream>>>(y1f, Wp2T, ab1, psum, psq, ymax, ymin);
    reduce_k<<<256, 256, 0, stream>>>(psum, psq, gamma2, beta2, ab2);
    final_k<<<dim3(64, 8, 4), 256, 0, stream>>>(ymax, ymin, ab2, out);
}

// Round 6
// 257.394 us; speedup vs baseline: 1.1159x; 1.1159x over previous
//
#include <hip/hip_runtime.h>

typedef unsigned short u16;
typedef unsigned int u32;
typedef __attribute__((ext_vector_type(8))) short bf16x8;
typedef __attribute__((ext_vector_type(4))) float f32x4;

#define NPTS 2048
#define CFEAT 256
#define NS 32
#define MTOT 262144           // 4*2048*32
#define GRID1 2048            // MTOT/128
#define GRID2 4096            // MTOT/64
#define INV_N (1.0f/262144.0f)

__device__ __forceinline__ float bf2f(u16 u) {
    union { u32 i; float f; } v; v.i = ((u32)u) << 16; return v.f;
}
__device__ __forceinline__ u16 f2bf(float f) {
    union { float f; u32 i; } v; v.f = f;
    u32 i = v.i;
    return (u16)((i + 0x7fffu + ((i >> 16) & 1u)) >> 16);
}

// async 1 KB wave copy: lds base wave-uniform, DMA lands at base + lane*16B
__device__ __forceinline__ void stage1k(u16* lds, const u16* g, int lane) {
    __builtin_amdgcn_global_load_lds((const __attribute__((address_space(1))) void*)(g + lane * 8),
                                     (__attribute__((address_space(3))) void*)lds, 16, 0, 0);
}

// ---------------- prep: LINEAR K-tiled weights (round-4 layout). WpT[ks][n(256)][kc(32)] ----------------
__global__ __launch_bounds__(256) void prep_k(const float* __restrict__ W1, const float* __restrict__ W2,
                                              u16* __restrict__ Wp1T, u16* __restrict__ Wp2T) {
    int o = blockIdx.x, t = threadIdx.x;
    int ks = t >> 5, kc = t & 31;
    Wp1T[(ks * 256 + o) * 32 + kc] = f2bf(W1[o * 259 + 3 + t]);
    Wp2T[(ks * 256 + o) * 32 + kc] = f2bf(W2[o * 256 + t]);
    if (t < 32) Wp1T[(8 * 256 + o) * 32 + t] = (t < 3) ? f2bf(W1[o * 259 + t]) : (u16)0;
}

// ---------------- cylinder query: wave per point, ballot compaction ----------------
__global__ __launch_bounds__(256) void query_k(const float* __restrict__ xyz, const float* __restrict__ rot,
                                               int* __restrict__ idx) {
    int pid = blockIdx.x * 4 + (threadIdx.x >> 6);
    int lane = threadIdx.x & 63;
    int b = pid >> 11, p = pid & 2047;
    const float* xb = xyz + (size_t)b * NPTS * 3;
    float px = xb[p * 3 + 0], py = xb[p * 3 + 1], pz = xb[p * 3 + 2];
    const float* rp = rot + (size_t)pid * 9;
    float r00 = rp[0], r01 = rp[1], r02 = rp[2];
    float r10 = rp[3], r11 = rp[4], r12 = rp[5];
    float r20 = rp[6], r21 = rp[7], r22 = rp[8];
    int cnt = 0, first = 0;
    for (int n0 = 0; n0 < NPTS && cnt < NS; n0 += 64) {
        int n = n0 + lane;
        float dx = __fsub_rn(xb[n * 3 + 0], px);
        float dy = __fsub_rn(xb[n * 3 + 1], py);
        float dz = __fsub_rn(xb[n * 3 + 2], pz);
        float a0 = __fadd_rn(__fadd_rn(__fmul_rn(r00, dx), __fmul_rn(r01, dy)), __fmul_rn(r02, dz));
        float a1 = __fadd_rn(__fadd_rn(__fmul_rn(r10, dx), __fmul_rn(r11, dy)), __fmul_rn(r12, dz));
        float a2 = __fadd_rn(__fadd_rn(__fmul_rn(r20, dx), __fmul_rn(r21, dy)), __fmul_rn(r22, dz));
        float t2 = __fadd_rn(__fmul_rn(a1, a1), __fmul_rn(a2, a2));
        bool valid = (t2 < 0.0025f) && (a0 > -0.02f) && (a0 < 0.04f);
        unsigned long long bal = __ballot(valid);
        if (cnt == 0 && bal) first = n0 + __builtin_ctzll(bal);
        int rank = __builtin_popcountll(bal & ((1ull << lane) - 1ull));
        int slot = cnt + rank;
        if (valid && slot < NS) idx[(size_t)pid * NS + slot] = n;
        cnt += __builtin_popcountll(bal);
    }
    int filled = cnt < NS ? cnt : NS;
    if (lane >= filled && lane < NS) idx[(size_t)pid * NS + lane] = (cnt > 0) ? first : 0;
}

// ---------------- features (B,C,N) fp32 -> featT (B,N,C) bf16 ----------------
__global__ __launch_bounds__(256) void featT_k(const float* __restrict__ feat, u16* __restrict__ featT) {
    __shared__ float sm[32 * 33];
    int b = blockIdx.z;
    int n0 = blockIdx.x * 32, c0 = blockIdx.y * 32;
    int t = threadIdx.x, x = t & 31, y = t >> 5;
    #pragma unroll
    for (int rr = 0; rr < 4; rr++) {
        int c = c0 + y + rr * 8;
        sm[(y + rr * 8) * 33 + x] = feat[((size_t)(b * CFEAT + c)) * NPTS + n0 + x];
    }
    __syncthreads();
    #pragma unroll
    for (int rr = 0; rr < 4; rr++) {
        int n = n0 + y + rr * 8;
        featT[((size_t)(b * NPTS + n)) * CFEAT + c0 + x] = f2bf(sm[x * 33 + (y + rr * 8)]);
    }
}

// ---------------- gxyz: rotated, scaled neighbor offsets, (MTOT,4) bf16 ----------------
__global__ __launch_bounds__(256) void gxyz_k(const float* __restrict__ xyz, const float* __restrict__ rot,
                                              const int* __restrict__ idx, u16* __restrict__ gxyz) {
    int m = blockIdx.x * 256 + threadIdx.x;
    int pid = m >> 5;
    int b = pid >> 11, p = pid & 2047;
    int i = idx[m];
    const float* xb = xyz + (size_t)b * NPTS * 3;
    float dx = (xb[i * 3 + 0] - xb[p * 3 + 0]) * 20.0f;
    float dy = (xb[i * 3 + 1] - xb[p * 3 + 1]) * 20.0f;
    float dz = (xb[i * 3 + 2] - xb[p * 3 + 2]) * 20.0f;
    const float* rp = rot + (size_t)pid * 9;
    float g0 = dx * rp[0] + dy * rp[3] + dz * rp[6];
    float g1 = dx * rp[1] + dy * rp[4] + dz * rp[7];
    float g2 = dx * rp[2] + dy * rp[5] + dz * rp[8];
    uint2 v;
    v.x = (u32)f2bf(g0) | ((u32)f2bf(g1) << 16);
    v.y = (u32)f2bf(g2);
    *(uint2*)(gxyz + (size_t)m * 4) = v;
}

// ---------------- pass 1: 128x256 GEMM1. A: ds_write dbuf (stride 40). B: linear DMA dbuf. ----------------
// epilogue: stats1 + y1 spill in round-4 canonical fragment layout ((mb*4+cb)*16+i*4+j)*64+lane
#define ASTR 40
__global__ __launch_bounds__(256, 2) void gemm1_k(
    const u16* __restrict__ featT, const u16* __restrict__ gxyz, const int* __restrict__ idx,
    const u16* __restrict__ Wp1T, float* __restrict__ psum, float* __restrict__ psq,
    uint2* __restrict__ y1f)
{
    __shared__ __attribute__((aligned(16))) u16 As[2][128 * ASTR];  // 20 KB
    __shared__ __attribute__((aligned(16))) u16 Bs[2][8192];        // 32 KB
    __shared__ int rowb[128];

    const int tid = threadIdx.x;
    const int lane = tid & 63, wave = tid >> 6;
    const int quad = lane >> 4, tl = lane & 15;
    const int wm = (wave & 1) * 64, wn = (wave >> 1) * 128;
    const int bx = blockIdx.x;
    const int m0 = bx * 128;
    const int srow = tid >> 1, shalf = tid & 1;

    if (tid < 128) {
        int m = m0 + tid;
        rowb[tid] = (m >> 16) * (NPTS * CFEAT) + idx[m] * CFEAT;
    }
    __syncthreads();

    // prologue: stage chunk 0 into buffer 0
    {
        const u16* p = featT + rowb[srow] + shalf * 16;
        *(uint4*)(&As[0][srow * ASTR + shalf * 16]) = *(const uint4*)p;
        *(uint4*)(&As[0][srow * ASTR + shalf * 16 + 8]) = *(const uint4*)(p + 8);
    }
    #pragma unroll
    for (int c = 0; c < 4; c++)
        stage1k(&Bs[0][wave * 2048 + c * 512], Wp1T + wave * 2048 + c * 512, lane);

    f32x4 acc[4][8];
    #pragma unroll
    for (int i = 0; i < 4; i++)
        #pragma unroll
        for (int j = 0; j < 8; j++) acc[i][j] = (f32x4){0.f, 0.f, 0.f, 0.f};

    for (int ks = 0; ks < 9; ks++) {
        __syncthreads();   // drains DMA (vmcnt) + ds_writes (lgkm) for chunk ks; others off old buffer
        const u16* Ab = As[ks & 1];
        const u16* Bb = Bs[ks & 1];
        bf16x8 af[4], bv[8];
        #pragma unroll
        for (int i = 0; i < 4; i++)
            af[i] = *(const bf16x8*)(Ab + (wm + i * 16 + tl) * ASTR + quad * 8);
        #pragma unroll
        for (int j = 0; j < 8; j++)
            bv[j] = *(const bf16x8*)(Bb + (wn + j * 16 + tl) * 32 + quad * 8);
        if (ks < 8) {      // stage chunk ks+1 into the other buffers; drains at next barrier
            u16* An = As[(ks + 1) & 1];
            u16* Bn = Bs[(ks + 1) & 1];
            const u16* gsrc = Wp1T + (ks + 1) * 8192;
            #pragma unroll
            for (int c = 0; c < 4; c++)
                stage1k(Bn + wave * 2048 + c * 512, gsrc + wave * 2048 + c * 512, lane);
            uint4 v0, v1;
            if (ks + 1 < 8) {
                const u16* p = featT + rowb[srow] + (ks + 1) * 32 + shalf * 16;
                v0 = *(const uint4*)p; v1 = *(const uint4*)(p + 8);
            } else {       // xyz chunk: row = [g0,g1,g2,0,...,0]
                v0 = make_uint4(0, 0, 0, 0); v1 = v0;
                if (shalf == 0) {
                    uint2 g2 = *(const uint2*)(gxyz + (size_t)(m0 + srow) * 4);
                    v0.x = g2.x; v0.y = g2.y;
                }
            }
            *(uint4*)(An + srow * ASTR + shalf * 16) = v0;
            *(uint4*)(An + srow * ASTR + shalf * 16 + 8) = v1;
        }
        #pragma unroll
        for (int j = 0; j < 8; j++)
            #pragma unroll
            for (int i = 0; i < 4; i++)
                acc[i][j] = __builtin_amdgcn_mfma_f32_16x16x32_bf16(af[i], bv[j], acc[i][j], 0, 0, 0);
    }

    // epilogue: y1 fragment spill (round-4 canonical index) + stats on rounded values
    const int mb = bx * 2 + (wave & 1);
    #pragma unroll
    for (int j = 0; j < 8; j++) {
        const int cb = (wave >> 1) * 2 + (j >> 2);
        float s = 0.f, q2 = 0.f;
        #pragma unroll
        for (int i = 0; i < 4; i++) {
            float v0 = acc[i][j][0], v1 = acc[i][j][1], v2 = acc[i][j][2], v3 = acc[i][j][3];
            u32 lo = (u32)f2bf(v0) | ((u32)f2bf(v1) << 16);
            u32 hi = (u32)f2bf(v2) | ((u32)f2bf(v3) << 16);
            y1f[(((size_t)mb * 4 + cb) * 16 + i * 4 + (j & 3)) * 64 + lane] = make_uint2(lo, hi);
            v0 = bf2f((u16)(lo & 0xffff)); v1 = bf2f((u16)(lo >> 16));
            v2 = bf2f((u16)(hi & 0xffff)); v3 = bf2f((u16)(hi >> 16));
            s += v0 + v1 + v2 + v3;
            q2 += v0 * v0 + v1 * v1 + v2 * v2 + v3 * v3;
        }
        s += __shfl_xor(s, 16); s += __shfl_xor(s, 32);
        q2 += __shfl_xor(q2, 16); q2 += __shfl_xor(q2, 32);
        if (quad == 0) {
            int col = wn + j * 16 + tl;
            psum[(size_t)mb * 256 + col] = s;
            psq[(size_t)mb * 256 + col] = q2;
        }
    }
}

// ---------------- pass 2 (round-4 proven): reload y1 frags, norm+relu -> LDS, GEMM2 (B DMA) ----------------
__global__ __launch_bounds__(256, 3) void gemm2_k(
    const uint2* __restrict__ y1f, const u16* __restrict__ Wp2T, const float* __restrict__ ab1,
    float* __restrict__ psum, float* __restrict__ psq,
    float* __restrict__ ymax, float* __restrict__ ymin)
{
    __shared__ __attribute__((aligned(16))) u16 Bs[8192];       // 16 KB
    __shared__ __attribute__((aligned(16))) u16 y1s[64 * 264];  // 33.8 KB
    const int tid = threadIdx.x;
    const int lane = tid & 63, wave = tid >> 6;
    const int quad = lane >> 4, tl = lane & 15;
    const int bx = blockIdx.x;

    // reload own pass-1 fragments (coalesced), normalize+relu, deposit to LDS (C-layout -> A-layout)
    #pragma unroll
    for (int j = 0; j < 4; j++) {
        int col = wave * 64 + j * 16 + tl;
        float a = ab1[col], bb = ab1[256 + col];
        #pragma unroll
        for (int i = 0; i < 4; i++) {
            uint2 v = y1f[((size_t)(bx * 4 + wave) * 16 + i * 4 + j) * 64 + lane];
            float f0 = bf2f((u16)(v.x & 0xffff)), f1 = bf2f((u16)(v.x >> 16));
            float f2 = bf2f((u16)(v.y & 0xffff)), f3 = bf2f((u16)(v.y >> 16));
            int rbi = (i * 16 + quad * 4) * 264 + col;
            y1s[rbi] = f2bf(fmaxf(fmaf(f0, a, bb), 0.f));
            y1s[rbi + 264] = f2bf(fmaxf(fmaf(f1, a, bb), 0.f));
            y1s[rbi + 528] = f2bf(fmaxf(fmaf(f2, a, bb), 0.f));
            y1s[rbi + 792] = f2bf(fmaxf(fmaf(f3, a, bb), 0.f));
        }
    }

    f32x4 acc2[4][4];
    #pragma unroll
    for (int i = 0; i < 4; i++)
        #pragma unroll
        for (int j = 0; j < 4; j++) acc2[i][j] = (f32x4){0.f, 0.f, 0.f, 0.f};

    for (int ks = 0; ks < 8; ks++) {
        const u16* gsrc = Wp2T + ks * 8192;
        #pragma unroll
        for (int c = 0; c < 4; c++)
            stage1k(Bs + wave * 2048 + c * 512, gsrc + wave * 2048 + c * 512, lane);
        __syncthreads();   // drains B(ks); first iter also covers y1s writes
        bf16x8 afv[4], bv[4];
        #pragma unroll
        for (int i = 0; i < 4; i++) afv[i] = *(const bf16x8*)(y1s + (i * 16 + tl) * 264 + ks * 32 + quad * 8);
        #pragma unroll
        for (int j = 0; j < 4; j++) bv[j] = *(const bf16x8*)(Bs + (wave * 64 + j * 16 + tl) * 32 + quad * 8);
        #pragma unroll
        for (int i = 0; i < 4; i++)
            #pragma unroll
            for (int j = 0; j < 4; j++)
                acc2[i][j] = __builtin_amdgcn_mfma_f32_16x16x32_bf16(afv[i], bv[j], acc2[i][j], 0, 0, 0);
        if (ks < 7) __syncthreads();   // readers done before Bs rewrite
    }

    #pragma unroll
    for (int j = 0; j < 4; j++) {
        int col = wave * 64 + j * 16 + tl;
        float s = 0.f, q2 = 0.f;
        float mx0 = -3.0e38f, mn0 = 3.0e38f, mx1 = -3.0e38f, mn1 = 3.0e38f;
        #pragma unroll
        for (int i = 0; i < 4; i++)
            #pragma unroll
            for (int r = 0; r < 4; r++) {
                float v = acc2[i][j][r];
                s += v; q2 += v * v;
                if (i < 2) { mx0 = fmaxf(mx0, v); mn0 = fminf(mn0, v); }
                else       { mx1 = fmaxf(mx1, v); mn1 = fminf(mn1, v); }
            }
        s += __shfl_xor(s, 16); s += __shfl_xor(s, 32);
        q2 += __shfl_xor(q2, 16); q2 += __shfl_xor(q2, 32);
        mx0 = fmaxf(mx0, __shfl_xor(mx0, 16)); mx0 = fmaxf(mx0, __shfl_xor(mx0, 32));
        mn0 = fminf(mn0, __shfl_xor(mn0, 16)); mn0 = fminf(mn0, __shfl_xor(mn0, 32));
        mx1 = fmaxf(mx1, __shfl_xor(mx1, 16)); mx1 = fmaxf(mx1, __shfl_xor(mx1, 32));
        mn1 = fminf(mn1, __shfl_xor(mn1, 16)); mn1 = fminf(mn1, __shfl_xor(mn1, 32));
        if (quad == 0) {
            psum[(size_t)bx * 256 + col] = s;
            psq[(size_t)bx * 256 + col] = q2;
            size_t p0 = (size_t)(bx * 2) * 256 + col;
            size_t p1 = (size_t)(bx * 2 + 1) * 256 + col;
            ymax[p0] = mx0; ymin[p0] = mn0;
            ymax[p1] = mx1; ymin[p1] = mn1;
        }
    }
}

// ---------------- reduce partials [4096][256] -> per-channel (a,b) ----------------
__global__ __launch_bounds__(256) void reduce_k(const float* __restrict__ psum, const float* __restrict__ psq,
                                                const float* __restrict__ gamma, const float* __restrict__ beta,
                                                float* __restrict__ ab) {
    __shared__ float red[8];
    int c = blockIdx.x, t = threadIdx.x;
    float s = 0.f, q = 0.f;
    for (int k = t; k < 4096; k += 256) { s += psum[(size_t)k * 256 + c]; q += psq[(size_t)k * 256 + c]; }
    #pragma unroll
    for (int o = 32; o >= 1; o >>= 1) { s += __shfl_xor(s, o); q += __shfl_xor(q, o); }
    int lane = t & 63, w = t >> 6;
    if (lane == 0) { red[w] = s; red[4 + w] = q; }
    __syncthreads();
    if (t == 0) {
        float S = red[0] + red[1] + red[2] + red[3];
        float Q = red[4] + red[5] + red[6] + red[7];
        float mu = S * INV_N;
        float var = Q * INV_N - mu * mu;
        float a = gamma[c] * rsqrtf(var + 1e-5f);
        ab[c] = a;
        ab[256 + c] = beta[c] - mu * a;
    }
}

// ---------------- final: relu(a*(a>=0?max:min)+b), transpose -> (B,O,N) ----------------
__global__ __launch_bounds__(256) void final_k(const float* __restrict__ ymax, const float* __restrict__ ymin,
                                               const float* __restrict__ ab, float* __restrict__ out) {
    __shared__ float sm[32 * 33];
    int b = blockIdx.z;
    int n0 = blockIdx.x * 32, o0 = blockIdx.y * 32;
    int t = threadIdx.x, x = t & 31, y = t >> 5;
    #pragma unroll
    for (int rr = 0; rr < 4; rr++) {
        int n = n0 + y + rr * 8;
        int o = o0 + x;
        float a = ab[o], bb = ab[256 + o];
        size_t p = (size_t)(b * NPTS + n) * 256 + o;
        float v = (a >= 0.f) ? ymax[p] : ymin[p];
        sm[(y + rr * 8) * 33 + x] = fmaxf(fmaf(v, a, bb), 0.f);
    }
    __syncthreads();
    #pragma unroll
    for (int rr = 0; rr < 4; rr++)
        out[((size_t)(b * 256 + o0 + y + rr * 8)) * NPTS + n0 + x] = sm[x * 33 + (y + rr * 8)];
}

extern "C" void kernel_launch(void* const* d_in, const int* in_sizes, int n_in,
                              void* d_out, int out_size, void* d_ws, size_t ws_size,
                              hipStream_t stream) {
    const float* xyz    = (const float*)d_in[0];
    const float* feat   = (const float*)d_in[1];
    const float* rot    = (const float*)d_in[2];
    const float* W1     = (const float*)d_in[3];
    const float* gamma1 = (const float*)d_in[4];
    const float* beta1  = (const float*)d_in[5];
    const float* W2     = (const float*)d_in[6];
    const float* gamma2 = (const float*)d_in[7];
    const float* beta2  = (const float*)d_in[8];
    float* out = (float*)d_out;

    char* ws = (char*)d_ws;
    u16*   featT = (u16*)(ws + 0);           //  4,194,304
    int*   idx   = (int*)(ws + 4194304);     //  1,048,576
    u16*   gxyz  = (u16*)(ws + 5242880);     //  2,097,152
    u16*   Wp1T  = (u16*)(ws + 7340032);     //    147,456
    u16*   Wp2T  = (u16*)(ws + 7487488);     //    131,072
    float* ab1   = (float*)(ws + 7618560);   //      2,048
    float* ab2   = (float*)(ws + 7620608);   //      2,048
    float* psum  = (float*)(ws + 7622656);   //  4,194,304
    float* psq   = (float*)(ws + 11816960);  //  4,194,304
    float* ymax  = (float*)(ws + 16011264);  //  8,388,608
    float* ymin  = (float*)(ws + 24399872);  //  8,388,608
    uint2* y1f   = (uint2*)(ws + 32788480);  // 134,217,728 (fragment layout)

    prep_k<<<256, 256, 0, stream>>>(W1, W2, Wp1T, Wp2T);
    query_k<<<2048, 256, 0, stream>>>(xyz, rot, idx);
    featT_k<<<dim3(64, 8, 4), 256, 0, stream>>>(feat, featT);
    gxyz_k<<<1024, 256, 0, stream>>>(xyz, rot, idx, gxyz);

    gemm1_k<<<GRID1, 256, 0, stream>>>(featT, gxyz, idx, Wp1T, psum, psq, y1f);
    reduce_k<<<256, 256, 0, stream>>>(psum, psq, gamma1, beta1, ab1);
    gemm2_k<<<GRID2, 256, 0, stream>>>(y1f, Wp2T, ab1, psum, psq, ymax, ymin);
    reduce_k<<<256, 256, 0, stream>>>(psum, psq, gamma2, beta2, ab2);
    final_k<<<dim3(64, 8, 4), 256, 0, stream>>>(ymax, ymin, ab2, out);
}